// Round 6
// baseline (275.523 us; speedup 1.0000x reference)
//
#include <hip/hip_runtime.h>

#define RR 12
#define LL 1728
#define CC 768
#define HEADS 12
#define HD 64
#define BATCH 4

typedef __attribute__((ext_vector_type(8))) short bf8;   // 8 x bf16
typedef __attribute__((ext_vector_type(4))) float f4;    // 4 x fp32

__device__ inline unsigned short f2bf(float x) {         // RNE-ish
  unsigned int u = __float_as_uint(x);
  return (unsigned short)((u + 0x7FFFu + ((u >> 16) & 1u)) >> 16);
}
__device__ inline unsigned short f2bfr(float x) {        // round-half-up (cheap)
  return (unsigned short)((__float_as_uint(x) + 0x8000u) >> 16);
}

__device__ inline float fast_exp2(float x) {
#if __has_builtin(__builtin_amdgcn_exp2f)
  return __builtin_amdgcn_exp2f(x);
#else
  return exp2f(x);
#endif
}

// async 16B global->LDS (wave-uniform LDS base + lane*16)
__device__ inline void gld16(const unsigned short* g, unsigned short* l) {
  __builtin_amdgcn_global_load_lds((const __attribute__((address_space(1))) unsigned int*)g,
                                   (__attribute__((address_space(3))) unsigned int*)l, 16, 0, 0);
}

#define QSCALE 0.1803368801111244f  /* 0.125 * log2(e): folds softmax base-2 conversion in */

// ---------------- prep: q,k -> bf16 (q pre-scaled); v -> vT[b][h][d][slot-permuted l] ----------------
// kv slot permutation sigma(s) = (s&3)*16 + (s>>2): applied to BOTH the P-store (A operand)
// and vT (B operand) -> MFMA K-dim permutation, result-invariant. Lets P be written as b64.
__global__ __launch_bounds__(256) void prep_kernel(const float* __restrict__ qkv,
                                                   unsigned short* __restrict__ qb,
                                                   unsigned short* __restrict__ kb,
                                                   unsigned short* __restrict__ vT) {
  __shared__ unsigned short tl[64 * 65];  // [d][l_local], stride 65
  const int lt = blockIdx.x;   // l tile 0..26
  const int h = blockIdx.y;
  const int b = blockIdx.z;
  const int t = threadIdx.x;

  // ---- q/k bf16 conversion for rows lt*64.., cols h*64.. ----
  {
    const int r0 = t >> 4;             // 0..15
    const int c4 = (t & 15) * 4;       // 0..60
#pragma unroll
    for (int p = 0; p < 4; ++p) {
      const int row = lt * 64 + p * 16 + r0;
      const size_t off = ((size_t)b * LL + row) * CC + h * HD + c4;
      const float4 qv = *(const float4*)(qkv + off);
      ushort4 oq;
      oq.x = f2bf(qv.x * QSCALE); oq.y = f2bf(qv.y * QSCALE);
      oq.z = f2bf(qv.z * QSCALE); oq.w = f2bf(qv.w * QSCALE);
      *(ushort4*)(qb + off) = oq;
      const float4 kv = *(const float4*)(qkv + (size_t)BATCH * LL * CC + off);
      ushort4 ok;
      ok.x = f2bf(kv.x); ok.y = f2bf(kv.y); ok.z = f2bf(kv.z); ok.w = f2bf(kv.w);
      *(ushort4*)(kb + off) = ok;
    }
  }

  // ---- vT with slot permutation ----
  const float* vsrc = qkv + ((size_t)(2 * BATCH + b)) * LL * CC;
#pragma unroll
  for (int it = 0; it < 4; ++it) {
    const int idx = it * 256 + t;
    const int lrow = idx >> 4;
    const int c4 = (idx & 15) * 4;
    const float4 vv = *(const float4*)(vsrc + (size_t)(lt * 64 + lrow) * CC + h * HD + c4);
    tl[(c4 + 0) * 65 + lrow] = f2bf(vv.x);
    tl[(c4 + 1) * 65 + lrow] = f2bf(vv.y);
    tl[(c4 + 2) * 65 + lrow] = f2bf(vv.z);
    tl[(c4 + 3) * 65 + lrow] = f2bf(vv.w);
  }
  __syncthreads();
#pragma unroll
  for (int it = 0; it < 4; ++it) {
    const int idx = it * 256 + t;
    const int drow = idx >> 4;
    const int s4 = (idx & 15) * 4;     // slot base (mult of 4)
    const int lb = s4 >> 2;            // sigma(s4+i) = i*16 + lb
    ushort4 o;
    o.x = tl[drow * 65 + lb];
    o.y = tl[drow * 65 + 16 + lb];
    o.z = tl[drow * 65 + 32 + lb];
    o.w = tl[drow * 65 + 48 + lb];
    *(ushort4*)(vT + (((size_t)(b * HEADS + h) * HD + drow) * LL) + lt * 64 + s4) = o;
  }
}

// ---------------- Flash attention + fused LePE conv (tap kt applied at K-iter kt) ----------------
__global__ __launch_bounds__(256) void attn_kernel(const unsigned short* __restrict__ qb,
                                                   const unsigned short* __restrict__ kb,
                                                   const unsigned short* __restrict__ vT,
                                                   const float* __restrict__ qkv,
                                                   const float* __restrict__ w,
                                                   const float* __restrict__ bias,
                                                   float* __restrict__ out) {
  __shared__ unsigned short k_lds[2][64 * 64];   // [buf][kv][d], XOR-swizzled chunks
  __shared__ unsigned short v_lds[2][64 * 64];   // [buf][d][slot], XOR-swizzled chunks
  __shared__ unsigned short p_lds[4][16 * 72];   // per-wave P [q][slot], stride 72
  __shared__ float w_lds[64 * 27];               // this head's depthwise weights (6.9 KB)

  const int qt = blockIdx.x;
  const int h = blockIdx.y;
  const int b = blockIdx.z;
  const int t = threadIdx.x;
  const int lane = t & 63;
  const int wave = t >> 6;
  const int m = lane & 15;
  const int quad = lane >> 4;

  // Q frags (pre-scaled bf16)
  bf8 qf[2];
  {
    const size_t qbase = ((size_t)(b * LL + qt * 64 + wave * 16 + m)) * CC + h * HD;
    qf[0] = *(const bf8*)(qb + qbase + quad * 8);
    qf[1] = *(const bf8*)(qb + qbase + 32 + quad * 8);
  }

  // stage this head's 64x27 weights (coalesced float4; visible after first loop barrier)
  {
    const float* wsrc = w + (size_t)h * HD * 27;  // 1728 floats, 16B-aligned
#pragma unroll
    for (int i = 0; i < 2; ++i) {
      const int idx = i * 256 + t;               // float4 index, 0..431
      if (idx < 432) *(float4*)&w_lds[idx * 4] = *(const float4*)&wsrc[idx * 4];
    }
  }

  // DMA source offsets: chunk cidx=(j*4+wave)*64+lane; row=cidx>>3; src chunk=(cidx&7)^(row&7)
  int koff[2], voff[2], ldsb[2];
#pragma unroll
  for (int j = 0; j < 2; ++j) {
    const int cidx = (j * 4 + wave) * 64 + lane;
    const int row = cidx >> 3;
    const int sc = (cidx & 7) ^ (row & 7);
    koff[j] = row * CC + sc * 8;
    voff[j] = row * LL + sc * 8;
    ldsb[j] = (j * 4 + wave) * 512;
  }

  const unsigned short* kgb = kb + (size_t)b * LL * CC + h * HD;
  const unsigned short* vgb = vT + ((size_t)(b * HEADS + h) * HD) * LL;

  // conv geometry: this thread's 4 rows (one per reg r), channels nt*16+m
  int zr[4], yr[4], xr[4];
#pragma unroll
  for (int r = 0; r < 4; ++r) {
    const int l = qt * 64 + wave * 16 + quad * 4 + r;
    zr[r] = l / (RR * RR);
    yr[r] = (l / RR) % RR;
    xr[r] = l % RR;
  }
  const float* vconv = qkv + ((size_t)(2 * BATCH + b)) * LL * CC + h * HD + m;

  // prologue: tile 0 -> buf 0
  gld16(kgb + koff[0], &k_lds[0][ldsb[0]]);
  gld16(kgb + koff[1], &k_lds[0][ldsb[1]]);
  gld16(vgb + voff[0], &v_lds[0][ldsb[0]]);
  gld16(vgb + voff[1], &v_lds[0][ldsb[1]]);

  f4 o_acc[4] = {};
  f4 lepe[4] = {};                        // lepe[nt][r], fp32
  float psum[4] = {0.f, 0.f, 0.f, 0.f};   // deferred softmax denominator (per-lane partial)

  // body for one K-tile; CUR compile-time so LDS addresses fold to immediates.
  // Conv tap KT is folded into iteration KT (27 taps == 27 K-tiles).
#define ATTN_BODY(KT, CUR)                                                              \
  {                                                                                     \
    __syncthreads(); /* implicit vmcnt(0): buf[CUR] ready; buf[CUR^1] free */           \
    if ((KT) < 26) {                                                                    \
      const size_t ko = (size_t)((KT) + 1) * 64 * CC;                                   \
      const int vo = ((KT) + 1) * 64;                                                   \
      gld16(kgb + ko + koff[0], &k_lds[(CUR) ^ 1][ldsb[0]]);                            \
      gld16(kgb + ko + koff[1], &k_lds[(CUR) ^ 1][ldsb[1]]);                            \
      gld16(vgb + vo + voff[0], &v_lds[(CUR) ^ 1][ldsb[0]]);                            \
      gld16(vgb + vo + voff[1], &v_lds[(CUR) ^ 1][ldsb[1]]);                            \
    }                                                                                   \
    f4 s_acc[4] = {};                                                                   \
    _Pragma("unroll")                                                                   \
    for (int nt = 0; nt < 4; ++nt) {                                                    \
      _Pragma("unroll")                                                                 \
      for (int ks = 0; ks < 2; ++ks) {                                                  \
        const int cc = ((ks * 4 + quad) ^ (m & 7)) * 8;                                 \
        const bf8 kf = *(const bf8*)&k_lds[CUR][(nt * 16 + m) * 64 + cc];               \
        s_acc[nt] = __builtin_amdgcn_mfma_f32_16x16x32_bf16(qf[ks], kf, s_acc[nt], 0, 0, 0); \
      }                                                                                 \
    }                                                                                   \
    { /* LePE tap KT: dz,dy,dx uniform; loads hide under MFMA latency */                \
      const int dz = (KT) / 9 - 1, dy = ((KT) % 9) / 3 - 1, dx = (KT) % 3 - 1;          \
      float wv[4];                                                                      \
      _Pragma("unroll")                                                                 \
      for (int nt = 0; nt < 4; ++nt) wv[nt] = w_lds[(nt * 16 + m) * 27 + (KT)];         \
      _Pragma("unroll")                                                                 \
      for (int r = 0; r < 4; ++r) {                                                     \
        const int zz = zr[r] + dz, yy = yr[r] + dy, xx = xr[r] + dx;                    \
        if (((unsigned)zz < RR) & ((unsigned)yy < RR) & ((unsigned)xx < RR)) {          \
          const float* vrow = vconv + (size_t)((zz * RR + yy) * RR + xx) * CC;          \
          _Pragma("unroll")                                                             \
          for (int nt = 0; nt < 4; ++nt) lepe[nt][r] += wv[nt] * vrow[nt * 16];         \
        }                                                                               \
      }                                                                                 \
    }                                                                                   \
    _Pragma("unroll")                                                                   \
    for (int r = 0; r < 4; ++r) {                                                       \
      const float p0 = fast_exp2(s_acc[0][r]);                                          \
      const float p1 = fast_exp2(s_acc[1][r]);                                          \
      const float p2 = fast_exp2(s_acc[2][r]);                                          \
      const float p3 = fast_exp2(s_acc[3][r]);                                          \
      psum[r] += (p0 + p1) + (p2 + p3);                                                 \
      ushort4 pk; /* slot m*4+nt holds kv nt*16+m (sigma-permuted, matches vT) */       \
      pk.x = f2bfr(p0); pk.y = f2bfr(p1); pk.z = f2bfr(p2); pk.w = f2bfr(p3);           \
      *(ushort4*)&p_lds[wave][(quad * 4 + r) * 72 + m * 4] = pk;                        \
    }                                                                                   \
    __asm__ volatile("s_waitcnt lgkmcnt(0)" ::: "memory"); /* p_lds wave-private */     \
    bf8 pf[2];                                                                          \
    _Pragma("unroll")                                                                   \
    for (int ks = 0; ks < 2; ++ks)                                                      \
      pf[ks] = *(const bf8*)&p_lds[wave][m * 72 + ks * 32 + quad * 8];                  \
    _Pragma("unroll")                                                                   \
    for (int nt = 0; nt < 4; ++nt) {                                                    \
      _Pragma("unroll")                                                                 \
      for (int ks = 0; ks < 2; ++ks) {                                                  \
        const int cc = ((ks * 4 + quad) ^ (m & 7)) * 8;                                 \
        const bf8 vf = *(const bf8*)&v_lds[CUR][(nt * 16 + m) * 64 + cc];               \
        o_acc[nt] = __builtin_amdgcn_mfma_f32_16x16x32_bf16(pf[ks], vf, o_acc[nt], 0, 0, 0); \
      }                                                                                 \
    }                                                                                   \
  }

  for (int ktp = 0; ktp < 13; ++ktp) {
    const int kt0 = ktp * 2;
    ATTN_BODY(kt0, 0)
    ATTN_BODY(kt0 + 1, 1)
  }
  ATTN_BODY(26, 0)
#undef ATTN_BODY

  // ---- epilogue: denominator reduce; out = O/l + lepe + bias (write-only) ----
  float bv[4];
#pragma unroll
  for (int nt = 0; nt < 4; ++nt) bv[nt] = bias[h * HD + nt * 16 + m];
#pragma unroll
  for (int r = 0; r < 4; ++r) {
    float s = psum[r];
    s += __shfl_xor(s, 1);
    s += __shfl_xor(s, 2);
    s += __shfl_xor(s, 4);
    s += __shfl_xor(s, 8);
    const float inv = 1.0f / s;
    const int row = qt * 64 + wave * 16 + quad * 4 + r;
    float* op = out + ((size_t)b * LL + row) * CC + h * HD;
#pragma unroll
    for (int nt = 0; nt < 4; ++nt)
      op[nt * 16 + m] = o_acc[nt][r] * inv + lepe[nt][r] + bv[nt];
  }
}

extern "C" void kernel_launch(void* const* d_in, const int* in_sizes, int n_in,
                              void* d_out, int out_size, void* d_ws, size_t ws_size,
                              hipStream_t stream) {
  (void)in_sizes; (void)n_in; (void)ws_size; (void)out_size;
  const float* qkv = (const float*)d_in[0];
  const float* lepe_w = (const float*)d_in[1];
  const float* lepe_b = (const float*)d_in[2];
  float* out = (float*)d_out;

  const size_t NE = (size_t)BATCH * LL * CC;
  unsigned short* qb = (unsigned short*)d_ws;
  unsigned short* kb = qb + NE;
  unsigned short* vT = kb + NE;  // 3*NE*2 B ~ 31.9 MB of ws

  prep_kernel<<<dim3(27, HEADS, BATCH), 256, 0, stream>>>(qkv, qb, kb, vT);
  attn_kernel<<<dim3(27, HEADS, BATCH), 256, 0, stream>>>(qb, kb, vT, qkv, lepe_w, lepe_b, out);
}

// Round 7
// 196.874 us; speedup vs baseline: 1.3995x; 1.3995x over previous
//
#include <hip/hip_runtime.h>

#define RR 12
#define LL 1728
#define CC 768
#define HEADS 12
#define HD 64
#define BATCH 4

typedef __attribute__((ext_vector_type(8))) short bf8;   // 8 x bf16
typedef __attribute__((ext_vector_type(4))) float f4;    // 4 x fp32

__device__ inline unsigned short f2bf(float x) {         // RNE-ish
  unsigned int u = __float_as_uint(x);
  return (unsigned short)((u + 0x7FFFu + ((u >> 16) & 1u)) >> 16);
}
__device__ inline unsigned short f2bfr(float x) {        // round-half-up (cheap)
  return (unsigned short)((__float_as_uint(x) + 0x8000u) >> 16);
}

__device__ inline float fast_exp2(float x) {
#if __has_builtin(__builtin_amdgcn_exp2f)
  return __builtin_amdgcn_exp2f(x);
#else
  return exp2f(x);
#endif
}

// async 16B global->LDS (wave-uniform LDS base + lane*16)
__device__ inline void gld16(const unsigned short* g, unsigned short* l) {
  __builtin_amdgcn_global_load_lds((const __attribute__((address_space(1))) unsigned int*)g,
                                   (__attribute__((address_space(3))) unsigned int*)l, 16, 0, 0);
}

#define QSCALE 0.1803368801111244f  /* 0.125 * log2(e): folds softmax base-2 conversion in */

// ---------------- tiny: w[C][27] -> w_t[27][C] so lepe weight loads coalesce ----------------
__global__ __launch_bounds__(256) void wt_kernel(const float* __restrict__ w,
                                                 float* __restrict__ w_t) {
  const int idx = blockIdx.x * 256 + threadIdx.x;  // 0..20735
  const int j = idx / CC;
  const int c = idx % CC;
  w_t[idx] = w[c * 27 + j];
}

// ---------------- prep: q,k -> bf16 (q pre-scaled); v -> vT[b][h][d][slot-permuted l] ----------------
// kv slot permutation sigma(s) = (s&3)*16 + (s>>2): applied to BOTH the P-store (A operand)
// and vT (B operand) -> MFMA K-dim permutation, result-invariant. Lets P be written as b64.
__global__ __launch_bounds__(256) void prep_kernel(const float* __restrict__ qkv,
                                                   unsigned short* __restrict__ qb,
                                                   unsigned short* __restrict__ kb,
                                                   unsigned short* __restrict__ vT) {
  __shared__ unsigned short tl[64 * 65];  // [d][l_local], stride 65
  const int lt = blockIdx.x;   // l tile 0..26
  const int h = blockIdx.y;
  const int b = blockIdx.z;
  const int t = threadIdx.x;

  // ---- q/k bf16 conversion for rows lt*64.., cols h*64.. ----
  {
    const int r0 = t >> 4;             // 0..15
    const int c4 = (t & 15) * 4;       // 0..60
#pragma unroll
    for (int p = 0; p < 4; ++p) {
      const int row = lt * 64 + p * 16 + r0;
      const size_t off = ((size_t)b * LL + row) * CC + h * HD + c4;
      const float4 qv = *(const float4*)(qkv + off);
      ushort4 oq;
      oq.x = f2bf(qv.x * QSCALE); oq.y = f2bf(qv.y * QSCALE);
      oq.z = f2bf(qv.z * QSCALE); oq.w = f2bf(qv.w * QSCALE);
      *(ushort4*)(qb + off) = oq;
      const float4 kv = *(const float4*)(qkv + (size_t)BATCH * LL * CC + off);
      ushort4 ok;
      ok.x = f2bf(kv.x); ok.y = f2bf(kv.y); ok.z = f2bf(kv.z); ok.w = f2bf(kv.w);
      *(ushort4*)(kb + off) = ok;
    }
  }

  // ---- vT with slot permutation ----
  const float* vsrc = qkv + ((size_t)(2 * BATCH + b)) * LL * CC;
#pragma unroll
  for (int it = 0; it < 4; ++it) {
    const int idx = it * 256 + t;
    const int lrow = idx >> 4;
    const int c4 = (idx & 15) * 4;
    const float4 vv = *(const float4*)(vsrc + (size_t)(lt * 64 + lrow) * CC + h * HD + c4);
    tl[(c4 + 0) * 65 + lrow] = f2bf(vv.x);
    tl[(c4 + 1) * 65 + lrow] = f2bf(vv.y);
    tl[(c4 + 2) * 65 + lrow] = f2bf(vv.z);
    tl[(c4 + 3) * 65 + lrow] = f2bf(vv.w);
  }
  __syncthreads();
#pragma unroll
  for (int it = 0; it < 4; ++it) {
    const int idx = it * 256 + t;
    const int drow = idx >> 4;
    const int s4 = (idx & 15) * 4;     // slot base (mult of 4)
    const int lb = s4 >> 2;            // sigma(s4+i) = i*16 + lb
    ushort4 o;
    o.x = tl[drow * 65 + lb];
    o.y = tl[drow * 65 + 16 + lb];
    o.z = tl[drow * 65 + 32 + lb];
    o.w = tl[drow * 65 + 48 + lb];
    *(ushort4*)(vT + (((size_t)(b * HEADS + h) * HD + drow) * LL) + lt * 64 + s4) = o;
  }
}

// ---------------- LePE: flat high-TLP version. Block = (zy-line, x-group-of-4, c-tile), 4 out/thread.
// Per (dz,dy) line: 6 masked x-loads (address-safe, unconditional -> one waitcnt batch) + 3 coalesced
// weight loads + 12 FMAs. No dependent chains; boundary handled by zeroing v, not branching. ----------
__global__ __launch_bounds__(256) void lepe_kernel(const float* __restrict__ qkv,
                                                   const float* __restrict__ w_t,
                                                   const float* __restrict__ bias,
                                                   float* __restrict__ out) {
  const int line = blockIdx.x / 3;          // 0..143 (z*12+y)
  const int xg = (blockIdx.x % 3) * 4;      // x0 in {0,4,8}
  const int z = line / RR;
  const int y = line % RR;
  const int c = blockIdx.y * 256 + threadIdx.x;
  const int b = blockIdx.z;
  const float* vb = qkv + ((size_t)(2 * BATCH + b)) * LL * CC + c;

  const float bv = bias[c];
  float acc[4] = {bv, bv, bv, bv};

#pragma unroll
  for (int dz = -1; dz <= 1; ++dz) {
#pragma unroll
    for (int dy = -1; dy <= 1; ++dy) {
      const int zz = z + dz, yy = y + dy;
      const bool lineok = ((unsigned)zz < RR) & ((unsigned)yy < RR);  // block-uniform
      const int base = (zz * RR + yy) * RR;
      // 6 x-positions xg-1 .. xg+4, masked loads
      float v6[6];
#pragma unroll
      for (int p = 0; p < 6; ++p) {
        const int xx = xg - 1 + p;
        const bool ok = lineok & ((unsigned)xx < RR);
        const int lp = ok ? base + xx : 0;               // address-safe
        const float vv = vb[(size_t)lp * CC];
        v6[p] = ok ? vv : 0.f;
      }
      const int jb = ((dz + 1) * 3 + (dy + 1)) * 3;      // tap base for this line
      const float wL = w_t[(jb + 0) * CC + c];
      const float wC = w_t[(jb + 1) * CC + c];
      const float wR = w_t[(jb + 2) * CC + c];
#pragma unroll
      for (int i = 0; i < 4; ++i)
        acc[i] += wL * v6[i] + wC * v6[i + 1] + wR * v6[i + 2];
    }
  }

  const size_t obase = ((size_t)b * LL + line * RR + xg) * CC + c;
#pragma unroll
  for (int i = 0; i < 4; ++i) out[obase + (size_t)i * CC] = acc[i];
}

// ---------------- Flash attention: dbuf DMA, exp2 softmax, deferred denominator (R5-verified) -------
__global__ __launch_bounds__(256) void attn_kernel(const unsigned short* __restrict__ qb,
                                                   const unsigned short* __restrict__ kb,
                                                   const unsigned short* __restrict__ vT,
                                                   float* __restrict__ out) {
  __shared__ unsigned short k_lds[2][64 * 64];   // [buf][kv][d], XOR-swizzled chunks
  __shared__ unsigned short v_lds[2][64 * 64];   // [buf][d][slot], XOR-swizzled chunks
  __shared__ unsigned short p_lds[4][16 * 72];   // per-wave P [q][slot], stride 72

  const int qt = blockIdx.x;
  const int h = blockIdx.y;
  const int b = blockIdx.z;
  const int t = threadIdx.x;
  const int lane = t & 63;
  const int wave = t >> 6;
  const int m = lane & 15;
  const int quad = lane >> 4;

  // Q frags (pre-scaled bf16)
  bf8 qf[2];
  {
    const size_t qbase = ((size_t)(b * LL + qt * 64 + wave * 16 + m)) * CC + h * HD;
    qf[0] = *(const bf8*)(qb + qbase + quad * 8);
    qf[1] = *(const bf8*)(qb + qbase + 32 + quad * 8);
  }

  // DMA source offsets: chunk cidx=(j*4+wave)*64+lane; row=cidx>>3; src chunk=(cidx&7)^(row&7)
  int koff[2], voff[2], ldsb[2];
#pragma unroll
  for (int j = 0; j < 2; ++j) {
    const int cidx = (j * 4 + wave) * 64 + lane;
    const int row = cidx >> 3;
    const int sc = (cidx & 7) ^ (row & 7);
    koff[j] = row * CC + sc * 8;
    voff[j] = row * LL + sc * 8;
    ldsb[j] = (j * 4 + wave) * 512;
  }

  const unsigned short* kgb = kb + (size_t)b * LL * CC + h * HD;
  const unsigned short* vgb = vT + ((size_t)(b * HEADS + h) * HD) * LL;

  // prologue: tile 0 -> buf 0
  gld16(kgb + koff[0], &k_lds[0][ldsb[0]]);
  gld16(kgb + koff[1], &k_lds[0][ldsb[1]]);
  gld16(vgb + voff[0], &v_lds[0][ldsb[0]]);
  gld16(vgb + voff[1], &v_lds[0][ldsb[1]]);

  f4 o_acc[4] = {};
  float psum[4] = {0.f, 0.f, 0.f, 0.f};   // deferred softmax denominator (per-lane partial)

  // body for one K-tile; CUR is compile-time so all LDS addresses fold to immediates
#define ATTN_BODY(KT, CUR)                                                              \
  {                                                                                     \
    __syncthreads(); /* implicit vmcnt(0): buf[CUR] ready; buf[CUR^1] free */           \
    if ((KT) < 26) {                                                                    \
      const size_t ko = (size_t)((KT) + 1) * 64 * CC;                                   \
      const int vo = ((KT) + 1) * 64;                                                   \
      gld16(kgb + ko + koff[0], &k_lds[(CUR) ^ 1][ldsb[0]]);                            \
      gld16(kgb + ko + koff[1], &k_lds[(CUR) ^ 1][ldsb[1]]);                            \
      gld16(vgb + vo + voff[0], &v_lds[(CUR) ^ 1][ldsb[0]]);                            \
      gld16(vgb + vo + voff[1], &v_lds[(CUR) ^ 1][ldsb[1]]);                            \
    }                                                                                   \
    f4 s_acc[4] = {};                                                                   \
    _Pragma("unroll")                                                                   \
    for (int nt = 0; nt < 4; ++nt) {                                                    \
      _Pragma("unroll")                                                                 \
      for (int ks = 0; ks < 2; ++ks) {                                                  \
        const int cc = ((ks * 4 + quad) ^ (m & 7)) * 8;                                 \
        const bf8 kf = *(const bf8*)&k_lds[CUR][(nt * 16 + m) * 64 + cc];               \
        s_acc[nt] = __builtin_amdgcn_mfma_f32_16x16x32_bf16(qf[ks], kf, s_acc[nt], 0, 0, 0); \
      }                                                                                 \
    }                                                                                   \
    _Pragma("unroll")                                                                   \
    for (int r = 0; r < 4; ++r) {                                                       \
      const float p0 = fast_exp2(s_acc[0][r]);                                          \
      const float p1 = fast_exp2(s_acc[1][r]);                                          \
      const float p2 = fast_exp2(s_acc[2][r]);                                          \
      const float p3 = fast_exp2(s_acc[3][r]);                                          \
      psum[r] += (p0 + p1) + (p2 + p3);                                                 \
      ushort4 pk; /* slot m*4+nt holds kv nt*16+m (sigma-permuted, matches vT) */       \
      pk.x = f2bfr(p0); pk.y = f2bfr(p1); pk.z = f2bfr(p2); pk.w = f2bfr(p3);           \
      *(ushort4*)&p_lds[wave][(quad * 4 + r) * 72 + m * 4] = pk;                        \
    }                                                                                   \
    __asm__ volatile("s_waitcnt lgkmcnt(0)" ::: "memory"); /* p_lds wave-private */     \
    bf8 pf[2];                                                                          \
    _Pragma("unroll")                                                                   \
    for (int ks = 0; ks < 2; ++ks)                                                      \
      pf[ks] = *(const bf8*)&p_lds[wave][m * 72 + ks * 32 + quad * 8];                  \
    _Pragma("unroll")                                                                   \
    for (int nt = 0; nt < 4; ++nt) {                                                    \
      _Pragma("unroll")                                                                 \
      for (int ks = 0; ks < 2; ++ks) {                                                  \
        const int cc = ((ks * 4 + quad) ^ (m & 7)) * 8;                                 \
        const bf8 vf = *(const bf8*)&v_lds[CUR][(nt * 16 + m) * 64 + cc];               \
        o_acc[nt] = __builtin_amdgcn_mfma_f32_16x16x32_bf16(pf[ks], vf, o_acc[nt], 0, 0, 0); \
      }                                                                                 \
    }                                                                                   \
  }

  for (int ktp = 0; ktp < 13; ++ktp) {
    const int kt0 = ktp * 2;
    ATTN_BODY(kt0, 0)
    ATTN_BODY(kt0 + 1, 1)
  }
  ATTN_BODY(26, 0)
#undef ATTN_BODY

  // ---- epilogue: single denominator reduce, then out += O / l (lepe already in out) ----
#pragma unroll
  for (int r = 0; r < 4; ++r) {
    float s = psum[r];
    s += __shfl_xor(s, 1);
    s += __shfl_xor(s, 2);
    s += __shfl_xor(s, 4);
    s += __shfl_xor(s, 8);
    const float inv = 1.0f / s;
    const int row = qt * 64 + wave * 16 + quad * 4 + r;
    float* op = out + ((size_t)b * LL + row) * CC + h * HD;
#pragma unroll
    for (int nt = 0; nt < 4; ++nt) {
      const int cix = nt * 16 + m;
      op[cix] = op[cix] + o_acc[nt][r] * inv;
    }
  }
}

extern "C" void kernel_launch(void* const* d_in, const int* in_sizes, int n_in,
                              void* d_out, int out_size, void* d_ws, size_t ws_size,
                              hipStream_t stream) {
  (void)in_sizes; (void)n_in; (void)ws_size; (void)out_size;
  const float* qkv = (const float*)d_in[0];
  const float* lepe_w = (const float*)d_in[1];
  const float* lepe_b = (const float*)d_in[2];
  float* out = (float*)d_out;

  const size_t NE = (size_t)BATCH * LL * CC;
  unsigned short* qb = (unsigned short*)d_ws;
  unsigned short* kb = qb + NE;
  unsigned short* vT = kb + NE;
  float* w_t = (float*)((char*)d_ws + 3 * NE * 2);  // 27x768 floats, 83 KB (16B-aligned)

  wt_kernel<<<dim3(CC * 27 / 256), 256, 0, stream>>>(lepe_w, w_t);
  prep_kernel<<<dim3(27, HEADS, BATCH), 256, 0, stream>>>(qkv, qb, kb, vT);
  lepe_kernel<<<dim3(144 * 3, CC / 256, BATCH), 256, 0, stream>>>(qkv, w_t, lepe_b, out);
  attn_kernel<<<dim3(27, HEADS, BATCH), 256, 0, stream>>>(qb, kb, vT, out);
}

// Round 8
// 192.593 us; speedup vs baseline: 1.4306x; 1.0222x over previous
//
#include <hip/hip_runtime.h>

#define RR 12
#define LL 1728
#define CC 768
#define HEADS 12
#define HD 64
#define BATCH 4

typedef __attribute__((ext_vector_type(8))) short bf8;   // 8 x bf16
typedef __attribute__((ext_vector_type(4))) float f4;    // 4 x fp32

__device__ inline unsigned short f2bf(float x) {         // RNE-ish
  unsigned int u = __float_as_uint(x);
  return (unsigned short)((u + 0x7FFFu + ((u >> 16) & 1u)) >> 16);
}
__device__ inline unsigned short f2bfr(float x) {        // round-half-up (cheap)
  return (unsigned short)((__float_as_uint(x) + 0x8000u) >> 16);
}

__device__ inline float fast_exp2(float x) {
#if __has_builtin(__builtin_amdgcn_exp2f)
  return __builtin_amdgcn_exp2f(x);
#else
  return exp2f(x);
#endif
}

// async 16B global->LDS (wave-uniform LDS base + lane*16)
__device__ inline void gld16(const unsigned short* g, unsigned short* l) {
  __builtin_amdgcn_global_load_lds((const __attribute__((address_space(1))) unsigned int*)g,
                                   (__attribute__((address_space(3))) unsigned int*)l, 16, 0, 0);
}

#define QSCALE 0.1803368801111244f  /* 0.125 * log2(e): folds softmax base-2 conversion in */

#define NLEPE 5184  /* 432 lines*xgroups x 3 ctiles x 4 batch */
#define NPREP 1296  /* 27 ltiles x 12 heads x 4 batch */

// ---------------- combined prep + lepe (block-uniform partition; 1 launch instead of 3) ------------
// blocks [0, NLEPE): LePE depthwise conv, writes conv+bias into out.
// blocks [NLEPE, NLEPE+NPREP): q,k -> bf16 (q pre-scaled by QSCALE); v -> vT[b][h][d][sigma(l)].
// kv slot permutation sigma(s) = (s&3)*16 + (s>>2): applied to BOTH P-store (A) and vT (B) -> MFMA
// K-dim permutation, result-invariant; lets attn write P as b64.
__global__ __launch_bounds__(256) void combined_kernel(const float* __restrict__ qkv,
                                                       const float* __restrict__ w,
                                                       const float* __restrict__ bias,
                                                       unsigned short* __restrict__ qb,
                                                       unsigned short* __restrict__ kb,
                                                       unsigned short* __restrict__ vT,
                                                       float* __restrict__ out) {
  __shared__ __align__(16) unsigned char smem[27648];  // union: lepe w-stage 27 KB / prep tl 8.3 KB
  const int bid = blockIdx.x;
  const int t = threadIdx.x;

  if (bid < NLEPE) {
    // ================= LePE =================
    const int xg = (bid % 3) * 4;            // x0 in {0,4,8}
    const int line = (bid / 3) % 144;        // z*12+y
    const int ct = (bid / 432) % 3;          // c-tile
    const int b = bid / 1296;
    const int z = line / RR;
    const int y = line % RR;
    const int c0 = ct * 256;
    const int c = c0 + t;
    float* w_lds = (float*)smem;

    // coalesced stage of w[c0*27 .. (c0+256)*27) as float4 (6912 floats)
    {
      const float* wsrc = w + (size_t)c0 * 27;
#pragma unroll
      for (int i = 0; i < 7; ++i) {
        const int idx = i * 256 + t;         // float4 index, 0..1727
        if (idx < 1728) *(float4*)&w_lds[idx * 4] = *(const float4*)&wsrc[idx * 4];
      }
    }
    __syncthreads();
    float wreg[27];
#pragma unroll
    for (int j = 0; j < 27; ++j) wreg[j] = w_lds[t * 27 + j];  // stride 27 ⊥ 32: 2-way, free

    const float* vb = qkv + ((size_t)(2 * BATCH + b)) * LL * CC + c;
    const float bv = bias[c];
    float acc[4] = {bv, bv, bv, bv};

#pragma unroll
    for (int dz = -1; dz <= 1; ++dz) {
#pragma unroll
      for (int dy = -1; dy <= 1; ++dy) {
        const int zz = z + dz, yy = y + dy;
        const bool lineok = ((unsigned)zz < RR) & ((unsigned)yy < RR);  // block-uniform
        const int base = (zz * RR + yy) * RR;
        float v6[6];                        // x-positions xg-1 .. xg+4, masked address-safe loads
#pragma unroll
        for (int p = 0; p < 6; ++p) {
          const int xx = xg - 1 + p;
          const bool ok = lineok & ((unsigned)xx < RR);
          const int lp = ok ? base + xx : 0;
          const float vv = vb[(size_t)lp * CC];
          v6[p] = ok ? vv : 0.f;
        }
        const int jb = ((dz + 1) * 3 + (dy + 1)) * 3;
        const float wL = wreg[jb], wC = wreg[jb + 1], wR = wreg[jb + 2];
#pragma unroll
        for (int i = 0; i < 4; ++i)
          acc[i] += wL * v6[i] + wC * v6[i + 1] + wR * v6[i + 2];
      }
    }
    const size_t obase = ((size_t)b * LL + line * RR + xg) * CC + c;
#pragma unroll
    for (int i = 0; i < 4; ++i) out[obase + (size_t)i * CC] = acc[i];

  } else {
    // ================= prep =================
    const int p = bid - NLEPE;
    const int lt = p % 27;
    const int h = (p / 27) % HEADS;
    const int b = p / (27 * HEADS);
    unsigned short* tl = (unsigned short*)smem;  // [d][l_local], stride 65

    // ---- q/k bf16 conversion for rows lt*64.., cols h*64.. ----
    {
      const int r0 = t >> 4;             // 0..15
      const int c4 = (t & 15) * 4;       // 0..60
#pragma unroll
      for (int pi = 0; pi < 4; ++pi) {
        const int row = lt * 64 + pi * 16 + r0;
        const size_t off = ((size_t)b * LL + row) * CC + h * HD + c4;
        const float4 qv = *(const float4*)(qkv + off);
        ushort4 oq;
        oq.x = f2bf(qv.x * QSCALE); oq.y = f2bf(qv.y * QSCALE);
        oq.z = f2bf(qv.z * QSCALE); oq.w = f2bf(qv.w * QSCALE);
        *(ushort4*)(qb + off) = oq;
        const float4 kv = *(const float4*)(qkv + (size_t)BATCH * LL * CC + off);
        ushort4 ok;
        ok.x = f2bf(kv.x); ok.y = f2bf(kv.y); ok.z = f2bf(kv.z); ok.w = f2bf(kv.w);
        *(ushort4*)(kb + off) = ok;
      }
    }

    // ---- vT with slot permutation ----
    const float* vsrc = qkv + ((size_t)(2 * BATCH + b)) * LL * CC;
#pragma unroll
    for (int it = 0; it < 4; ++it) {
      const int idx = it * 256 + t;
      const int lrow = idx >> 4;
      const int c4 = (idx & 15) * 4;
      const float4 vv = *(const float4*)(vsrc + (size_t)(lt * 64 + lrow) * CC + h * HD + c4);
      tl[(c4 + 0) * 65 + lrow] = f2bf(vv.x);
      tl[(c4 + 1) * 65 + lrow] = f2bf(vv.y);
      tl[(c4 + 2) * 65 + lrow] = f2bf(vv.z);
      tl[(c4 + 3) * 65 + lrow] = f2bf(vv.w);
    }
    __syncthreads();
#pragma unroll
    for (int it = 0; it < 4; ++it) {
      const int idx = it * 256 + t;
      const int drow = idx >> 4;
      const int s4 = (idx & 15) * 4;     // slot base (mult of 4)
      const int lb = s4 >> 2;            // sigma(s4+i) = i*16 + lb
      ushort4 o;
      o.x = tl[drow * 65 + lb];
      o.y = tl[drow * 65 + 16 + lb];
      o.z = tl[drow * 65 + 32 + lb];
      o.w = tl[drow * 65 + 48 + lb];
      *(ushort4*)(vT + (((size_t)(b * HEADS + h) * HD + drow) * LL) + lt * 64 + s4) = o;
    }
  }
}

// ---------------- Flash attention: dbuf DMA, exp2 softmax, deferred denominator (R5-verified) -------
__global__ __launch_bounds__(256) void attn_kernel(const unsigned short* __restrict__ qb,
                                                   const unsigned short* __restrict__ kb,
                                                   const unsigned short* __restrict__ vT,
                                                   float* __restrict__ out) {
  __shared__ unsigned short k_lds[2][64 * 64];   // [buf][kv][d], XOR-swizzled chunks
  __shared__ unsigned short v_lds[2][64 * 64];   // [buf][d][slot], XOR-swizzled chunks
  __shared__ unsigned short p_lds[4][16 * 72];   // per-wave P [q][slot], stride 72

  const int qt = blockIdx.x;
  const int h = blockIdx.y;
  const int b = blockIdx.z;
  const int t = threadIdx.x;
  const int lane = t & 63;
  const int wave = t >> 6;
  const int m = lane & 15;
  const int quad = lane >> 4;

  // Q frags (pre-scaled bf16)
  bf8 qf[2];
  {
    const size_t qbase = ((size_t)(b * LL + qt * 64 + wave * 16 + m)) * CC + h * HD;
    qf[0] = *(const bf8*)(qb + qbase + quad * 8);
    qf[1] = *(const bf8*)(qb + qbase + 32 + quad * 8);
  }

  // DMA source offsets: chunk cidx=(j*4+wave)*64+lane; row=cidx>>3; src chunk=(cidx&7)^(row&7)
  int koff[2], voff[2], ldsb[2];
#pragma unroll
  for (int j = 0; j < 2; ++j) {
    const int cidx = (j * 4 + wave) * 64 + lane;
    const int row = cidx >> 3;
    const int sc = (cidx & 7) ^ (row & 7);
    koff[j] = row * CC + sc * 8;
    voff[j] = row * LL + sc * 8;
    ldsb[j] = (j * 4 + wave) * 512;
  }

  const unsigned short* kgb = kb + (size_t)b * LL * CC + h * HD;
  const unsigned short* vgb = vT + ((size_t)(b * HEADS + h) * HD) * LL;

  // prologue: tile 0 -> buf 0
  gld16(kgb + koff[0], &k_lds[0][ldsb[0]]);
  gld16(kgb + koff[1], &k_lds[0][ldsb[1]]);
  gld16(vgb + voff[0], &v_lds[0][ldsb[0]]);
  gld16(vgb + voff[1], &v_lds[0][ldsb[1]]);

  f4 o_acc[4] = {};
  float psum[4] = {0.f, 0.f, 0.f, 0.f};   // deferred softmax denominator (per-lane partial)

  // body for one K-tile; CUR is compile-time so all LDS addresses fold to immediates
#define ATTN_BODY(KT, CUR)                                                              \
  {                                                                                     \
    __syncthreads(); /* implicit vmcnt(0): buf[CUR] ready; buf[CUR^1] free */           \
    if ((KT) < 26) {                                                                    \
      const size_t ko = (size_t)((KT) + 1) * 64 * CC;                                   \
      const int vo = ((KT) + 1) * 64;                                                   \
      gld16(kgb + ko + koff[0], &k_lds[(CUR) ^ 1][ldsb[0]]);                            \
      gld16(kgb + ko + koff[1], &k_lds[(CUR) ^ 1][ldsb[1]]);                            \
      gld16(vgb + vo + voff[0], &v_lds[(CUR) ^ 1][ldsb[0]]);                            \
      gld16(vgb + vo + voff[1], &v_lds[(CUR) ^ 1][ldsb[1]]);                            \
    }                                                                                   \
    f4 s_acc[4] = {};                                                                   \
    _Pragma("unroll")                                                                   \
    for (int nt = 0; nt < 4; ++nt) {                                                    \
      _Pragma("unroll")                                                                 \
      for (int ks = 0; ks < 2; ++ks) {                                                  \
        const int cc = ((ks * 4 + quad) ^ (m & 7)) * 8;                                 \
        const bf8 kf = *(const bf8*)&k_lds[CUR][(nt * 16 + m) * 64 + cc];               \
        s_acc[nt] = __builtin_amdgcn_mfma_f32_16x16x32_bf16(qf[ks], kf, s_acc[nt], 0, 0, 0); \
      }                                                                                 \
    }                                                                                   \
    _Pragma("unroll")                                                                   \
    for (int r = 0; r < 4; ++r) {                                                       \
      const float p0 = fast_exp2(s_acc[0][r]);                                          \
      const float p1 = fast_exp2(s_acc[1][r]);                                          \
      const float p2 = fast_exp2(s_acc[2][r]);                                          \
      const float p3 = fast_exp2(s_acc[3][r]);                                          \
      psum[r] += (p0 + p1) + (p2 + p3);                                                 \
      ushort4 pk; /* slot m*4+nt holds kv nt*16+m (sigma-permuted, matches vT) */       \
      pk.x = f2bfr(p0); pk.y = f2bfr(p1); pk.z = f2bfr(p2); pk.w = f2bfr(p3);           \
      *(ushort4*)&p_lds[wave][(quad * 4 + r) * 72 + m * 4] = pk;                        \
    }                                                                                   \
    __asm__ volatile("s_waitcnt lgkmcnt(0)" ::: "memory"); /* p_lds wave-private */     \
    bf8 pf[2];                                                                          \
    _Pragma("unroll")                                                                   \
    for (int ks = 0; ks < 2; ++ks)                                                      \
      pf[ks] = *(const bf8*)&p_lds[wave][m * 72 + ks * 32 + quad * 8];                  \
    _Pragma("unroll")                                                                   \
    for (int nt = 0; nt < 4; ++nt) {                                                    \
      _Pragma("unroll")                                                                 \
      for (int ks = 0; ks < 2; ++ks) {                                                  \
        const int cc = ((ks * 4 + quad) ^ (m & 7)) * 8;                                 \
        const bf8 vf = *(const bf8*)&v_lds[CUR][(nt * 16 + m) * 64 + cc];               \
        o_acc[nt] = __builtin_amdgcn_mfma_f32_16x16x32_bf16(pf[ks], vf, o_acc[nt], 0, 0, 0); \
      }                                                                                 \
    }                                                                                   \
  }

  for (int ktp = 0; ktp < 13; ++ktp) {
    const int kt0 = ktp * 2;
    ATTN_BODY(kt0, 0)
    ATTN_BODY(kt0 + 1, 1)
  }
  ATTN_BODY(26, 0)
#undef ATTN_BODY

  // ---- epilogue: single denominator reduce, then out += O / l (lepe already in out) ----
#pragma unroll
  for (int r = 0; r < 4; ++r) {
    float s = psum[r];
    s += __shfl_xor(s, 1);
    s += __shfl_xor(s, 2);
    s += __shfl_xor(s, 4);
    s += __shfl_xor(s, 8);
    const float inv = 1.0f / s;
    const int row = qt * 64 + wave * 16 + quad * 4 + r;
    float* op = out + ((size_t)b * LL + row) * CC + h * HD;
#pragma unroll
    for (int nt = 0; nt < 4; ++nt) {
      const int cix = nt * 16 + m;
      op[cix] = op[cix] + o_acc[nt][r] * inv;
    }
  }
}

extern "C" void kernel_launch(void* const* d_in, const int* in_sizes, int n_in,
                              void* d_out, int out_size, void* d_ws, size_t ws_size,
                              hipStream_t stream) {
  (void)in_sizes; (void)n_in; (void)ws_size; (void)out_size;
  const float* qkv = (const float*)d_in[0];
  const float* lepe_w = (const float*)d_in[1];
  const float* lepe_b = (const float*)d_in[2];
  float* out = (float*)d_out;

  const size_t NE = (size_t)BATCH * LL * CC;
  unsigned short* qb = (unsigned short*)d_ws;
  unsigned short* kb = qb + NE;
  unsigned short* vT = kb + NE;  // 3*NE*2 B ~ 31.9 MB of ws

  combined_kernel<<<dim3(NLEPE + NPREP), 256, 0, stream>>>(qkv, lepe_w, lepe_b, qb, kb, vT, out);
  attn_kernel<<<dim3(27, HEADS, BATCH), 256, 0, stream>>>(qb, kb, vT, out);
}